// Round 13
// baseline (783.927 us; speedup 1.0000x reference)
//
#include <hip/hip_runtime.h>
#include <hip/hip_cooperative_groups.h>

namespace cg = cooperative_groups;

#define N_NODES 100000
#define N_EDGES 3200000
#define F_IN 128
#define F_OUT 16

#define NSEG 512                 // binning segments (== grid size, 1:1)
#define EPS (N_EDGES / NSEG)     // 6250 edges/segment (exact)
#define EPT 13                   // max edges per thread (ceil(6250/512))
#define NBUCK 512                // destination buckets (== grid size, 1:1)
#define NPB 196                  // nodes per bucket: 196*512 = 100352 >= N
#define CAPR 7424                // bucket capacity (mean 6250, +15 sigma)
#define RPT 15                   // sort records per thread (ceil(7424/512))
#define RPT3 29                  // fallback sortB (256 thr)
#define GEMM32 ((N_NODES + 31) / 32)        // 3125 gemm chunks (32 nodes each)
#define PULL_BLOCKS 2048
#define NPAIR ((N_NODES + 1) / 2)

// ---- ws layout (bytes) ----
#define OFF_CUR   0x000000u   // NBUCK ints: bucket fill counts (zeroed in P0)
#define OFF_NPTR  0x010000u   // N ints: per-node run start (absolute csr idx)
#define OFF_NCNT  0x080000u   // N ints: per-node run length
#define OFF_DINV  0x0F0000u   // N floats
#define OFF_HH    0x160000u   // N*16 floats (6.4 MB)
#define OFF_GG    0x780000u   // N*16 ushorts (3.2 MB), bf16
#define OFF_CSR   0xB00000u   // NBUCK*CAPR int2 (29 MiB), bucket regions
#define WS_NEEDED ((size_t)0x1000000 + (size_t)N_EDGES * 8)

__device__ __forceinline__ unsigned short f2bf(float f) {
    unsigned u = __float_as_uint(f);
    unsigned r = (u + 0x7FFFu + ((u >> 16) & 1u)) >> 16;   // RNE
    return (unsigned short)r;
}
__device__ __forceinline__ float bf2f(unsigned short v) {
    return __uint_as_float((unsigned)v << 16);
}

// ============ main path: ONE cooperative kernel ============
// R3: LDS atomics lane-serial -> 1 ret-atomic per edge per phase.
// R4/R6/R10: scattered cross-XCD stores & global atomics amplify/serialize.
// R12 ledger: kernel work ~150us vs 224 total -> ~60-80us is inter-dispatch
// overhead. R13: fuse memset+bin+gemm+sort+pull into one cooperative launch
// with grid.sync() (fence = same L2 wb/inv a kernel boundary does).

__global__ void __launch_bounds__(512, 4) k_fused(
        const int* __restrict__ row, const int* __restrict__ col,
        const float* __restrict__ ew, int* __restrict__ cursor,
        int2* __restrict__ csr, const float* __restrict__ x,
        const float* __restrict__ W, float* __restrict__ h,
        float* __restrict__ dinv, unsigned short* __restrict__ gb,
        int* __restrict__ nodeptr, int* __restrict__ ncnt,
        const float* __restrict__ bias, float* __restrict__ out) {
    __shared__ int smem[2048];        // P1: lcnt[512]+gofs[512] | Ws 8KB
    __shared__ int cnt[256];
    __shared__ int basel[256];
    __shared__ int wtot4[4];
    __shared__ float dl[256];
    cg::grid_group grid = cg::this_grid();
    int tid = threadIdx.x;
    int b = blockIdx.x;

    // ---- P0: zero bucket cursors (replaces host memset; handles cold ws) ----
    if (tid == 0) atomicExch(&cursor[b], 0);
    grid.sync();
    __threadfence();

    // ---- P1a: bin segment b (binA logic: 1 LDS ret-atomic/edge, direct
    //           scattered write into reserved bucket region) ----
    {
        int* lcnt = smem;
        int* gofs = smem + 512;
        int e0 = b * EPS;
        lcnt[tid] = 0;
        __syncthreads();

        int2 rec[EPT];
        int meta[EPT];
#pragma unroll
        for (int k = 0; k < EPT; ++k) {
            int i = k * 512 + tid;
            if (k < EPT - 1 || i < EPS) {
                int e = e0 + i;
                int r = row[e];
                int c = col[e];
                float w = ew[e];
                int bk = c / NPB;
                int pos = atomicAdd(&lcnt[bk], 1);          // native, ret
                rec[k] = make_int2((r << 8) | (c - bk * NPB), __float_as_int(w));
                meta[k] = (bk << 16) | pos;
            }
        }
        __syncthreads();

        int v = lcnt[tid];
        gofs[tid] = tid * CAPR + atomicAdd(&cursor[tid], v);  // global reserve
        __syncthreads();

#pragma unroll
        for (int k = 0; k < EPT; ++k) {
            int i = k * 512 + tid;
            if (k < EPT - 1 || i < EPS) {
                int m = meta[k];
                csr[gofs[m >> 16] + (m & 0xFFFF)] = rec[k];
            }
        }
        __syncthreads();
    }

    // ---- P1b: grid-strided GEMM chunks (h = x@W, 32 nodes per chunk) ----
    {
        float* Ws = (float*)smem;
        for (int i = tid; i < F_IN * F_OUT; i += 512) Ws[i] = W[i];
        __syncthreads();
        int j = tid & 15;
        int nl = tid >> 4;          // 0..31 node-lane within chunk
        for (int g = b; g < GEMM32; g += NSEG) {
            int n = g * 32 + nl;
            if (n < N_NODES) {
                const float4* xr = (const float4*)(x + (size_t)n * F_IN);
                float acc = 0.0f;
#pragma unroll
                for (int k4 = 0; k4 < F_IN / 4; ++k4) {
                    float4 xv = xr[k4];
                    int k = k4 * 4;
                    acc += xv.x * Ws[(k + 0) * F_OUT + j];
                    acc += xv.y * Ws[(k + 1) * F_OUT + j];
                    acc += xv.z * Ws[(k + 2) * F_OUT + j];
                    acc += xv.w * Ws[(k + 3) * F_OUT + j];
                }
                h[(size_t)n * F_OUT + j] = acc;
            }
        }
    }

    __threadfence();
    grid.sync();
    __threadfence();

    // ---- P2: sort bucket b (sortB logic @512 thr: 1 LDS ret-atomic/edge,
    //          direct rewrite into own exclusive region, wsum, dinv, gb) ----
    {
        int c0 = b * NPB;
        int rb = b * CAPR;
        int total = cursor[b];
        if (total > CAPR) total = CAPR;         // statistically unreachable

        if (tid < 256) cnt[tid] = 0;
        __syncthreads();

        int2 rec[RPT];
        int pos[RPT];
#pragma unroll
        for (int k = 0; k < RPT; ++k) {
            int i = k * 512 + tid;
            if (i < total) {
                rec[k] = csr[rb + i];           // coalesced read
                pos[k] = atomicAdd(&cnt[rec[k].x & 255], 1);
            }
        }
        __syncthreads();

        int v = 0, inc = 0;
        if (tid < 256) {
            v = cnt[tid];
            inc = v;
#pragma unroll
            for (int off = 1; off < 64; off <<= 1) {
                int t = __shfl_up(inc, off);
                if ((tid & 63) >= off) inc += t;
            }
            if ((tid & 63) == 63) wtot4[tid >> 6] = inc;
        }
        __syncthreads();
        int excl = 0;
        if (tid < 256) {
            int woff = 0;
#pragma unroll
            for (int k = 0; k < 4; ++k)
                if (k < (tid >> 6)) woff += wtot4[k];
            excl = woff + inc - v;
            int n = c0 + tid;
            if (tid < NPB && n < N_NODES) {
                nodeptr[n] = rb + excl;
                ncnt[n] = v;
            }
            basel[tid] = excl;
        }
        __syncthreads();

#pragma unroll
        for (int k = 0; k < RPT; ++k) {
            int i = k * 512 + tid;
            if (i < total) {
                int cl = rec[k].x & 255;
                csr[rb + basel[cl] + pos[k]] = make_int2(rec[k].x >> 8, rec[k].y);
            }
        }
        __syncthreads();   // vmcnt drained before barrier -> rewrite visible

        float d = 0.0f;
        if (tid < NPB && (c0 + tid) < N_NODES) {
            float s0 = 1.0f, s1 = 0.0f, s2 = 0.0f, s3 = 0.0f; // 1.0 = self-loop
            const int2* run = csr + rb + excl;
            int k = 0;
            for (; k + 4 <= v; k += 4) {
                s0 += __int_as_float(run[k + 0].y);
                s1 += __int_as_float(run[k + 1].y);
                s2 += __int_as_float(run[k + 2].y);
                s3 += __int_as_float(run[k + 3].y);
            }
            for (; k < v; ++k) s0 += __int_as_float(run[k].y);
            d = rsqrtf((s0 + s1) + (s2 + s3));
            dinv[c0 + tid] = d;
        }
        if (tid < 256) dl[tid] = d;
        __syncthreads();
        for (int i = tid; i < NPB * F_OUT; i += 512) {
            int idx = c0 * F_OUT + i;
            if (idx < N_NODES * F_OUT) gb[idx] = f2bf(dl[i >> 4] * h[idx]);
        }
    }

    __threadfence();
    grid.sync();
    __threadfence();

    // ---- P3: pull, TWO nodes per wave (pull5 logic; 4096 global waves) ----
    {
        int gw = b * 8 + (tid >> 6);
        int lane = tid & 63;
        int half = lane >> 5;
        int l32 = lane & 31;
        int l4 = lane & 15;
        int fr = ((l4 & 1) << 3) | ((l4 & 2) << 1) | ((l4 & 4) >> 1) | ((l4 & 8) >> 3);
        float bj = bias[fr];
        for (int q = gw; q < NPAIR; q += NSEG * 8) {
            int n = q * 2 + half;
            bool valid = (n < N_NODES);
            int p0 = valid ? nodeptr[n] : 0;
            int c = valid ? ncnt[n] : 0;
            float acc[16];
#pragma unroll
            for (int k = 0; k < 16; ++k) acc[k] = 0.0f;
            int2 rec = (l32 < c) ? csr[p0 + l32] : make_int2(0, 0);    // prime
            for (int base = 0; base < c; base += 32) {
                int2 cur = rec;
                int ni = base + 32 + l32;
                rec = (ni < c) ? csr[p0 + ni] : make_int2(0, 0);       // prefetch
                float w = __int_as_float(cur.y);
                const uint4* gr = (const uint4*)(gb + ((size_t)cur.x << 4));
                uint4 qa = gr[0];
                uint4 qb = gr[1];
                acc[0]  += w * __uint_as_float(qa.x << 16);
                acc[1]  += w * __uint_as_float(qa.x & 0xFFFF0000u);
                acc[2]  += w * __uint_as_float(qa.y << 16);
                acc[3]  += w * __uint_as_float(qa.y & 0xFFFF0000u);
                acc[4]  += w * __uint_as_float(qa.z << 16);
                acc[5]  += w * __uint_as_float(qa.z & 0xFFFF0000u);
                acc[6]  += w * __uint_as_float(qa.w << 16);
                acc[7]  += w * __uint_as_float(qa.w & 0xFFFF0000u);
                acc[8]  += w * __uint_as_float(qb.x << 16);
                acc[9]  += w * __uint_as_float(qb.x & 0xFFFF0000u);
                acc[10] += w * __uint_as_float(qb.y << 16);
                acc[11] += w * __uint_as_float(qb.y & 0xFFFF0000u);
                acc[12] += w * __uint_as_float(qb.z << 16);
                acc[13] += w * __uint_as_float(qb.z & 0xFFFF0000u);
                acc[14] += w * __uint_as_float(qb.w << 16);
                acc[15] += w * __uint_as_float(qb.w & 0xFFFF0000u);
            }
            bool b1 = (lane & 1) != 0;
#pragma unroll
            for (int k = 0; k < 8; ++k) {
                float keep = b1 ? acc[k + 8] : acc[k];
                float send = b1 ? acc[k] : acc[k + 8];
                acc[k] = keep + __shfl_xor(send, 1);
            }
            bool b2 = (lane & 2) != 0;
#pragma unroll
            for (int k = 0; k < 4; ++k) {
                float keep = b2 ? acc[k + 4] : acc[k];
                float send = b2 ? acc[k] : acc[k + 4];
                acc[k] = keep + __shfl_xor(send, 2);
            }
            bool b4 = (lane & 4) != 0;
#pragma unroll
            for (int k = 0; k < 2; ++k) {
                float keep = b4 ? acc[k + 2] : acc[k];
                float send = b4 ? acc[k] : acc[k + 2];
                acc[k] = keep + __shfl_xor(send, 4);
            }
            bool b8 = (lane & 8) != 0;
            {
                float keep = b8 ? acc[1] : acc[0];
                float send = b8 ? acc[0] : acc[1];
                acc[0] = keep + __shfl_xor(send, 8);
            }
            acc[0] += __shfl_xor(acc[0], 16);
            if (l32 < 16 && valid) {
                float d = dinv[n];
                float gs = bf2f(gb[(size_t)n * F_OUT + fr]);
                out[(size_t)n * F_OUT + fr] = bj + d * (gs + acc[0]);
            }
        }
    }
}

// ============ proven 3-kernel path (R12) — hedge if coop launch fails ======

__global__ void __launch_bounds__(512) k_binA(const int* __restrict__ row,
                                              const int* __restrict__ col,
                                              const float* __restrict__ ew,
                                              int* __restrict__ cursor,
                                              int2* __restrict__ csr,
                                              const float* __restrict__ x,
                                              const float* __restrict__ W,
                                              float* __restrict__ h) {
    __shared__ int smem[2048];
    int tid = threadIdx.x;
    if (blockIdx.x < NSEG) {
        int* lcnt = smem;
        int* gofs = smem + 512;
        int e0 = blockIdx.x * EPS;
        lcnt[tid] = 0;
        __syncthreads();
        int2 rec[EPT];
        int meta[EPT];
#pragma unroll
        for (int k = 0; k < EPT; ++k) {
            int i = k * 512 + tid;
            if (k < EPT - 1 || i < EPS) {
                int e = e0 + i;
                int r = row[e];
                int c = col[e];
                float w = ew[e];
                int bk = c / NPB;
                int pos = atomicAdd(&lcnt[bk], 1);
                rec[k] = make_int2((r << 8) | (c - bk * NPB), __float_as_int(w));
                meta[k] = (bk << 16) | pos;
            }
        }
        __syncthreads();
        int v = lcnt[tid];
        gofs[tid] = tid * CAPR + atomicAdd(&cursor[tid], v);
        __syncthreads();
#pragma unroll
        for (int k = 0; k < EPT; ++k) {
            int i = k * 512 + tid;
            if (k < EPT - 1 || i < EPS) {
                int m = meta[k];
                csr[gofs[m >> 16] + (m & 0xFFFF)] = rec[k];
            }
        }
    } else {
        float* Ws = (float*)smem;
        for (int i = tid; i < F_IN * F_OUT; i += 512) Ws[i] = W[i];
        __syncthreads();
        int n = (blockIdx.x - NSEG) * 32 + (tid >> 4);
        int j = tid & 15;
        if (n >= N_NODES) return;
        const float4* xr = (const float4*)(x + (size_t)n * F_IN);
        float acc = 0.0f;
#pragma unroll
        for (int k4 = 0; k4 < F_IN / 4; ++k4) {
            float4 xv = xr[k4];
            int k = k4 * 4;
            acc += xv.x * Ws[(k + 0) * F_OUT + j];
            acc += xv.y * Ws[(k + 1) * F_OUT + j];
            acc += xv.z * Ws[(k + 2) * F_OUT + j];
            acc += xv.w * Ws[(k + 3) * F_OUT + j];
        }
        h[(size_t)n * F_OUT + j] = acc;
    }
}

__global__ void __launch_bounds__(256) k_sortB(const int* __restrict__ cursor,
                                               int2* __restrict__ csr,
                                               const float* __restrict__ h,
                                               float* __restrict__ dinv,
                                               unsigned short* __restrict__ gb,
                                               int* __restrict__ nodeptr,
                                               int* __restrict__ ncnt) {
    __shared__ int cnt[256];
    __shared__ int basel[256];
    __shared__ int wtot[4];
    __shared__ float dl[256];
    int tid = threadIdx.x;
    int b = blockIdx.x;
    int c0 = b * NPB;
    int rb = b * CAPR;
    int total = cursor[b];
    if (total > CAPR) total = CAPR;
    cnt[tid] = 0;
    __syncthreads();
    int2 rec[RPT3];
    int pos[RPT3];
#pragma unroll
    for (int k = 0; k < RPT3; ++k) {
        int i = k * 256 + tid;
        if (i < total) {
            rec[k] = csr[rb + i];
            pos[k] = atomicAdd(&cnt[rec[k].x & 255], 1);
        }
    }
    __syncthreads();
    int v = cnt[tid];
    int inc = v;
#pragma unroll
    for (int off = 1; off < 64; off <<= 1) {
        int t = __shfl_up(inc, off);
        if ((tid & 63) >= off) inc += t;
    }
    if ((tid & 63) == 63) wtot[tid >> 6] = inc;
    __syncthreads();
    int woff = 0;
#pragma unroll
    for (int k = 0; k < 4; ++k)
        if (k < (tid >> 6)) woff += wtot[k];
    int excl = woff + inc - v;
    int n = c0 + tid;
    if (tid < NPB && n < N_NODES) {
        nodeptr[n] = rb + excl;
        ncnt[n] = v;
    }
    basel[tid] = excl;
    __syncthreads();
#pragma unroll
    for (int k = 0; k < RPT3; ++k) {
        int i = k * 256 + tid;
        if (i < total) {
            int cl = rec[k].x & 255;
            csr[rb + basel[cl] + pos[k]] = make_int2(rec[k].x >> 8, rec[k].y);
        }
    }
    __syncthreads();
    float d = 0.0f;
    if (tid < NPB && n < N_NODES) {
        float s0 = 1.0f, s1 = 0.0f, s2 = 0.0f, s3 = 0.0f;
        const int2* run = csr + rb + excl;
        int k = 0;
        for (; k + 4 <= v; k += 4) {
            s0 += __int_as_float(run[k + 0].y);
            s1 += __int_as_float(run[k + 1].y);
            s2 += __int_as_float(run[k + 2].y);
            s3 += __int_as_float(run[k + 3].y);
        }
        for (; k < v; ++k) s0 += __int_as_float(run[k].y);
        d = rsqrtf((s0 + s1) + (s2 + s3));
        dinv[n] = d;
    }
    dl[tid] = d;
    __syncthreads();
    for (int i = tid; i < NPB * F_OUT; i += 256) {
        int idx = c0 * F_OUT + i;
        if (idx < N_NODES * F_OUT) gb[idx] = f2bf(dl[i >> 4] * h[idx]);
    }
}

__global__ void __launch_bounds__(256) k_pull5(const int* __restrict__ nodeptr,
                                               const int* __restrict__ ncnt,
                                               const int2* __restrict__ csr,
                                               const unsigned short* __restrict__ gb,
                                               const float* __restrict__ dinv,
                                               const float* __restrict__ bias,
                                               float* __restrict__ out) {
    int wid = threadIdx.x >> 6;
    int lane = threadIdx.x & 63;
    int half = lane >> 5;
    int l32 = lane & 31;
    int l4 = lane & 15;
    int fr = ((l4 & 1) << 3) | ((l4 & 2) << 1) | ((l4 & 4) >> 1) | ((l4 & 8) >> 3);
    float bj = bias[fr];
    for (int q = blockIdx.x * 4 + wid; q < NPAIR; q += PULL_BLOCKS * 4) {
        int n = q * 2 + half;
        bool valid = (n < N_NODES);
        int p0 = valid ? nodeptr[n] : 0;
        int c = valid ? ncnt[n] : 0;
        float acc[16];
#pragma unroll
        for (int k = 0; k < 16; ++k) acc[k] = 0.0f;
        int2 rec = (l32 < c) ? csr[p0 + l32] : make_int2(0, 0);
        for (int base = 0; base < c; base += 32) {
            int2 cur = rec;
            int ni = base + 32 + l32;
            rec = (ni < c) ? csr[p0 + ni] : make_int2(0, 0);
            float w = __int_as_float(cur.y);
            const uint4* gr = (const uint4*)(gb + ((size_t)cur.x << 4));
            uint4 qa = gr[0];
            uint4 qb = gr[1];
            acc[0]  += w * __uint_as_float(qa.x << 16);
            acc[1]  += w * __uint_as_float(qa.x & 0xFFFF0000u);
            acc[2]  += w * __uint_as_float(qa.y << 16);
            acc[3]  += w * __uint_as_float(qa.y & 0xFFFF0000u);
            acc[4]  += w * __uint_as_float(qa.z << 16);
            acc[5]  += w * __uint_as_float(qa.z & 0xFFFF0000u);
            acc[6]  += w * __uint_as_float(qa.w << 16);
            acc[7]  += w * __uint_as_float(qa.w & 0xFFFF0000u);
            acc[8]  += w * __uint_as_float(qb.x << 16);
            acc[9]  += w * __uint_as_float(qb.x & 0xFFFF0000u);
            acc[10] += w * __uint_as_float(qb.y << 16);
            acc[11] += w * __uint_as_float(qb.y & 0xFFFF0000u);
            acc[12] += w * __uint_as_float(qb.z << 16);
            acc[13] += w * __uint_as_float(qb.z & 0xFFFF0000u);
            acc[14] += w * __uint_as_float(qb.w << 16);
            acc[15] += w * __uint_as_float(qb.w & 0xFFFF0000u);
        }
        bool b1 = (lane & 1) != 0;
#pragma unroll
        for (int k = 0; k < 8; ++k) {
            float keep = b1 ? acc[k + 8] : acc[k];
            float send = b1 ? acc[k] : acc[k + 8];
            acc[k] = keep + __shfl_xor(send, 1);
        }
        bool b2 = (lane & 2) != 0;
#pragma unroll
        for (int k = 0; k < 4; ++k) {
            float keep = b2 ? acc[k + 4] : acc[k];
            float send = b2 ? acc[k] : acc[k + 4];
            acc[k] = keep + __shfl_xor(send, 2);
        }
        bool b4 = (lane & 4) != 0;
#pragma unroll
        for (int k = 0; k < 2; ++k) {
            float keep = b4 ? acc[k + 2] : acc[k];
            float send = b4 ? acc[k] : acc[k + 2];
            acc[k] = keep + __shfl_xor(send, 4);
        }
        bool b8 = (lane & 8) != 0;
        {
            float keep = b8 ? acc[1] : acc[0];
            float send = b8 ? acc[0] : acc[1];
            acc[0] = keep + __shfl_xor(send, 8);
        }
        acc[0] += __shfl_xor(acc[0], 16);
        if (l32 < 16 && valid) {
            float d = dinv[n];
            float gs = bf2f(gb[(size_t)n * F_OUT + fr]);
            out[(size_t)n * F_OUT + fr] = bj + d * (gs + acc[0]);
        }
    }
}

// ============ fallback path (small ws; proven; fp32 g) ============

#define EDGE_BLOCKS_FB ((N_EDGES + 255) / 256)
#define GEMM_BLOCKS_FB ((N_NODES + 15) / 16)
__global__ void k_init_fb(float* __restrict__ deg) {
    int i = blockIdx.x * blockDim.x + threadIdx.x;
    if (i < N_NODES) deg[i] = 1.0f;
}
__global__ void k_fused_fb(const int* __restrict__ col, const float* __restrict__ ew,
                           float* __restrict__ deg, const float* __restrict__ x,
                           const float* __restrict__ W, float* __restrict__ h) {
    int b3 = blockIdx.x / 3;
    int r3 = blockIdx.x % 3;
    if (r3 < 2) {
        int e = (b3 * 2 + r3) * 256 + threadIdx.x;
        if (e < N_EDGES) atomicAdd(&deg[col[e]], ew[e]);
    } else {
        __shared__ float Ws[F_IN * F_OUT];
        int tid = threadIdx.x;
        for (int i = tid; i < F_IN * F_OUT; i += 256) Ws[i] = W[i];
        __syncthreads();
        int n = b3 * 16 + (tid >> 4);
        int j = tid & 15;
        if (n >= N_NODES) return;
        const float4* xr = (const float4*)(x + (size_t)n * F_IN);
        float acc = 0.0f;
#pragma unroll
        for (int k4 = 0; k4 < F_IN / 4; ++k4) {
            float4 xv = xr[k4];
            int k = k4 * 4;
            acc += xv.x * Ws[(k + 0) * F_OUT + j];
            acc += xv.y * Ws[(k + 1) * F_OUT + j];
            acc += xv.z * Ws[(k + 2) * F_OUT + j];
            acc += xv.w * Ws[(k + 3) * F_OUT + j];
        }
        h[(size_t)n * F_OUT + j] = acc;
    }
}
__global__ void k_final_fb(float* __restrict__ deg, const float* __restrict__ h,
                           const float* __restrict__ b, float* __restrict__ g,
                           float* __restrict__ out) {
    int i = blockIdx.x * blockDim.x + threadIdx.x;
    int n = i >> 4;
    int j = i & 15;
    if (n >= N_NODES) return;
    float d = rsqrtf(deg[n]);
    if (j == 0) deg[n] = d;
    float gg = d * h[i];
    g[i] = gg;
    out[i] = b[j] + d * gg;
}
__global__ void k_scatter_fb(const int* __restrict__ row, const int* __restrict__ col,
                             const float* __restrict__ ew, const float* __restrict__ dinv,
                             const float* __restrict__ g, float* __restrict__ out) {
    long long tid = (long long)blockIdx.x * blockDim.x + threadIdx.x;
    int e = (int)(tid >> 4);
    int j = (int)(tid & 15);
    if (e >= N_EDGES) return;
    int c = col[e];
    float norm = ew[e] * dinv[c];
    atomicAdd(&out[(size_t)c * F_OUT + j], g[(size_t)row[e] * F_OUT + j] * norm);
}

extern "C" void kernel_launch(void* const* d_in, const int* in_sizes, int n_in,
                              void* d_out, int out_size, void* d_ws, size_t ws_size,
                              hipStream_t stream) {
    const float* x  = (const float*)d_in[0];
    const int*   ei = (const int*)d_in[1];   // [2, N_EDGES] int32
    const float* ew = (const float*)d_in[2];
    const float* W  = (const float*)d_in[3];
    const float* b  = (const float*)d_in[4];
    float* out = (float*)d_out;

    const int* row = ei;            // edge_index[0] = source
    const int* col = ei + N_EDGES;  // edge_index[1] = destination

    char* ws = (char*)d_ws;
    dim3 blk(256);

    if (ws_size >= WS_NEEDED) {
        int*   cur  = (int*)(ws + OFF_CUR);
        int*   nptr = (int*)(ws + OFF_NPTR);
        int*   ncnt = (int*)(ws + OFF_NCNT);
        float* dinv = (float*)(ws + OFF_DINV);
        float* h    = (float*)(ws + OFF_HH);
        unsigned short* gb = (unsigned short*)(ws + OFF_GG);
        int2*  csr  = (int2*)(ws + OFF_CSR);

        void* args[] = {(void*)&row, (void*)&col, (void*)&ew, (void*)&cur,
                        (void*)&csr, (void*)&x, (void*)&W, (void*)&h,
                        (void*)&dinv, (void*)&gb, (void*)&nptr, (void*)&ncnt,
                        (void*)&b, (void*)&out};
        hipError_t e = hipLaunchCooperativeKernel((const void*)k_fused,
                                                  dim3(NSEG), dim3(512),
                                                  args, 0, stream);
        if (e != hipSuccess) {
            // hedge: proven R12 3-kernel sequence
            hipMemsetAsync(cur, 0, NBUCK * sizeof(int), stream);
            k_binA<<<NSEG + GEMM32, 512, 0, stream>>>(row, col, ew, cur, csr, x, W, h);
            k_sortB<<<NBUCK, blk, 0, stream>>>(cur, csr, h, dinv, gb, nptr, ncnt);
            k_pull5<<<PULL_BLOCKS, blk, 0, stream>>>(nptr, ncnt, csr, gb, dinv, b, out);
        }
    } else {
        float* deg = (float*)ws;
        float* h   = (float*)(ws + (1u << 20));
        float* g   = (float*)(ws + (8u << 20));
        k_init_fb<<<(N_NODES + 255) / 256, blk, 0, stream>>>(deg);
        k_fused_fb<<<EDGE_BLOCKS_FB + GEMM_BLOCKS_FB, blk, 0, stream>>>(col, ew, deg, x, W, h);
        k_final_fb<<<(N_NODES * F_OUT + 255) / 256, blk, 0, stream>>>(deg, h, b, g, out);
        long long total = (long long)N_EDGES * F_OUT;
        k_scatter_fb<<<(unsigned)((total + 255) / 256), blk, 0, stream>>>(row, col, ew, deg, g, out);
    }
}